// Round 1
// baseline (1495.926 us; speedup 1.0000x reference)
//
#include <hip/hip_runtime.h>
#include <cmath>

// Problem constants (fixed by setup_inputs)
constexpr int S = 128;   // num_states
constexpr int C = 32;    // num_chains
constexpr int N = 4096;  // num_nodes
constexpr int T = 512;   // num_iters

// Output layout (flat float32, concatenated in reference return order)
constexpr size_t OFF1 = 0;                          // log_observed_state_probs  [T,N]
constexpr size_t OFF2 = OFF1 + (size_t)T * N;       // log_observed_state_probs_ [T,C,N]
constexpr size_t OFF3 = OFF2 + (size_t)T * C * N;   // log_hidden_state_probs   [T,C,S]
constexpr size_t OFF4 = OFF3 + (size_t)T * C * S;   // log_emission             [S,N]
constexpr size_t OFF5 = OFF4 + (size_t)S * N;       // log_chain_weights        [T,C]

// Workspace layout (floats). Total = 11,026,432 floats = ~44.1 MB
constexpr size_t WS_PE  = 0;                         // pE  [S,N]  exp(log_emission)
constexpr size_t WS_PCW = WS_PE + (size_t)S * N;     // pcw [T,C]  exp(log_chain_weights)
constexpr size_t WS_H   = WS_PCW + (size_t)T * C;    // H   [T,C,S] prob-domain hidden states
constexpr size_t WS_PW  = WS_H + (size_t)T * C * S;  // Pw  [512][S,S] powers of transition (slot t = P^t, slot 0 unused)

// ---------------------------------------------------------------------------
// Row log-softmax: block per row, 256 threads. Writes log_softmax (optional)
// and exp(log_softmax) = softmax (optional).
// ---------------------------------------------------------------------------
__global__ void row_softmax_kernel(const float* __restrict__ in,
                                   float* __restrict__ log_out,
                                   float* __restrict__ p_out,
                                   int cols) {
    const int row = blockIdx.x;
    const float* x = in + (size_t)row * cols;
    const int tid = threadIdx.x;

    __shared__ float sm[4];
    __shared__ float ss[4];

    float m = -INFINITY;
    for (int j = tid; j < cols; j += 256) m = fmaxf(m, x[j]);
#pragma unroll
    for (int o = 32; o > 0; o >>= 1) m = fmaxf(m, __shfl_xor(m, o, 64));
    const int wid = tid >> 6;
    if ((tid & 63) == 0) sm[wid] = m;
    __syncthreads();
    m = fmaxf(fmaxf(sm[0], sm[1]), fmaxf(sm[2], sm[3]));

    float s = 0.f;
    for (int j = tid; j < cols; j += 256) s += expf(x[j] - m);
#pragma unroll
    for (int o = 32; o > 0; o >>= 1) s += __shfl_xor(s, o, 64);
    if ((tid & 63) == 0) ss[wid] = s;
    __syncthreads();
    s = ss[0] + ss[1] + ss[2] + ss[3];

    const float lse = m + logf(s);
    for (int j = tid; j < cols; j += 256) {
        const float v = x[j] - lse;
        if (log_out) log_out[(size_t)row * cols + j] = v;
        if (p_out)  p_out[(size_t)row * cols + j] = expf(v);
    }
}

// ---------------------------------------------------------------------------
// Powers-of-P doubling round: computes P^(half+j) = P^j * P^half, j=1..count.
// grid = (8 row-blocks of 16 rows, count matrices), block = 256.
// Thread computes 8 rows x 1 col. A-loads are wave-uniform (L1 broadcast).
// ---------------------------------------------------------------------------
__global__ void power_round_kernel(float* __restrict__ Pw, int half, int count) {
    const int j  = blockIdx.y + 1;            // 1..count
    const int rb = blockIdx.x;                // 0..7
    const float* A = Pw + (size_t)j * (S * S);        // P^j
    const float* B = Pw + (size_t)half * (S * S);     // P^half
    float* D = Pw + (size_t)(half + j) * (S * S);     // P^(half+j)

    const int col = threadIdx.x & 127;
    const int rg  = threadIdx.x >> 7;         // 0..1
    const int row0 = rb * 16 + rg * 8;

    float acc[8] = {0.f, 0.f, 0.f, 0.f, 0.f, 0.f, 0.f, 0.f};
    for (int k = 0; k < S; k += 4) {
        const float b0 = B[(size_t)(k + 0) * S + col];
        const float b1 = B[(size_t)(k + 1) * S + col];
        const float b2 = B[(size_t)(k + 2) * S + col];
        const float b3 = B[(size_t)(k + 3) * S + col];
#pragma unroll
        for (int r = 0; r < 8; r++) {
            const float4 a = *reinterpret_cast<const float4*>(&A[(size_t)(row0 + r) * S + k]);
            acc[r] = fmaf(a.x, b0, fmaf(a.y, b1, fmaf(a.z, b2, fmaf(a.w, b3, acc[r]))));
        }
    }
#pragma unroll
    for (int r = 0; r < 8; r++) D[(size_t)(row0 + r) * S + col] = acc[r];
}

// ---------------------------------------------------------------------------
// Hidden states: H_t = H_0 * P^t (prob domain), t = 1..511, all parallel.
// Writes prob-domain H to ws and log(H) to output 3.
// grid = 511 (t), block = 256: col = s' (128), rg covers 16 chains each.
// ---------------------------------------------------------------------------
__global__ void hidden_kernel(const float* __restrict__ H0,
                              const float* __restrict__ Pw,
                              float* __restrict__ Hall,
                              float* __restrict__ out3) {
    const int t = blockIdx.x + 1;
    const float* B = Pw + (size_t)t * (S * S);   // P^t

    const int col = threadIdx.x & 127;
    const int rg  = threadIdx.x >> 7;            // 0..1 -> chains rg*16..rg*16+15

    float acc[16];
#pragma unroll
    for (int r = 0; r < 16; r++) acc[r] = 0.f;

    for (int k = 0; k < S; k += 4) {
        const float b0 = B[(size_t)(k + 0) * S + col];
        const float b1 = B[(size_t)(k + 1) * S + col];
        const float b2 = B[(size_t)(k + 2) * S + col];
        const float b3 = B[(size_t)(k + 3) * S + col];
#pragma unroll
        for (int r = 0; r < 16; r++) {
            const float4 a = *reinterpret_cast<const float4*>(&H0[(size_t)(rg * 16 + r) * S + k]);
            acc[r] = fmaf(a.x, b0, fmaf(a.y, b1, fmaf(a.z, b2, fmaf(a.w, b3, acc[r]))));
        }
    }
#pragma unroll
    for (int r = 0; r < 16; r++) {
        const int c = rg * 16 + r;
        const float p = acc[r];
        Hall[((size_t)t * C + c) * S + col] = p;
        out3[((size_t)t * C + c) * S + col] = logf(p);
    }
}

// ---------------------------------------------------------------------------
// Observation GEMM + fused epilogue:
//   O[c,n] = sum_s H_t[c,s] * pE[s,n]     (prob domain)
//   out2[t,c,n] = log(O[c,n])
//   out1[t,n]   = log(sum_c pcw[t,c] * O[c,n])
// grid = (32 n-tiles of 128, 512 t), block = 256: col = n (128), rg -> 16 c's.
// ---------------------------------------------------------------------------
__global__ void obs_kernel(const float* __restrict__ Hall,
                           const float* __restrict__ pE,
                           const float* __restrict__ pcw,
                           float* __restrict__ out1,
                           float* __restrict__ out2) {
    const int t  = blockIdx.y;
    const int n0 = blockIdx.x * 128;
    const int col = threadIdx.x & 127;
    const int rg  = threadIdx.x >> 7;
    const int n = n0 + col;
    const float* H = Hall + (size_t)t * C * S;

    float acc[16];
#pragma unroll
    for (int r = 0; r < 16; r++) acc[r] = 0.f;

    for (int k = 0; k < S; k += 4) {
        const float e0 = pE[(size_t)(k + 0) * N + n];
        const float e1 = pE[(size_t)(k + 1) * N + n];
        const float e2 = pE[(size_t)(k + 2) * N + n];
        const float e3 = pE[(size_t)(k + 3) * N + n];
#pragma unroll
        for (int r = 0; r < 16; r++) {
            const float4 a = *reinterpret_cast<const float4*>(&H[(size_t)(rg * 16 + r) * S + k]);
            acc[r] = fmaf(a.x, e0, fmaf(a.y, e1, fmaf(a.z, e2, fmaf(a.w, e3, acc[r]))));
        }
    }

    float partial = 0.f;
#pragma unroll
    for (int r = 0; r < 16; r++) {
        const int c = rg * 16 + r;
        const float o = acc[r];
        out2[((size_t)t * C + c) * N + n] = logf(o);
        partial = fmaf(pcw[(size_t)t * C + c], o, partial);
    }

    __shared__ float sred[2][128];
    sred[rg][col] = partial;
    __syncthreads();
    if (rg == 0) {
        out1[(size_t)t * N + n] = logf(sred[0][col] + sred[1][col]);
    }
}

// ---------------------------------------------------------------------------
extern "C" void kernel_launch(void* const* d_in, const int* in_sizes, int n_in,
                              void* d_out, int out_size, void* d_ws, size_t ws_size,
                              hipStream_t stream) {
    const float* in_init  = (const float*)d_in[0];  // [C,S]
    const float* in_cw    = (const float*)d_in[1];  // [T,C]
    const float* in_emis  = (const float*)d_in[2];  // [S,N]
    const float* in_trans = (const float*)d_in[3];  // [S,S]
    // d_in[4] = num_iters (hardcoded T=512)

    float* out = (float*)d_out;
    float* ws  = (float*)d_ws;   // requires ~44.1 MB

    float* ws_pE  = ws + WS_PE;
    float* ws_pcw = ws + WS_PCW;
    float* ws_H   = ws + WS_H;
    float* ws_Pw  = ws + WS_PW;

    // 1) Softmaxes: log parts go straight into outputs, prob parts into ws.
    row_softmax_kernel<<<128, 256, 0, stream>>>(in_emis,  out + OFF4, ws_pE, N);
    row_softmax_kernel<<<T,   256, 0, stream>>>(in_cw,    out + OFF5, ws_pcw, C);
    row_softmax_kernel<<<128, 256, 0, stream>>>(in_trans, nullptr,    ws_Pw + (size_t)S * S, S);
    row_softmax_kernel<<<C,   256, 0, stream>>>(in_init,  out + OFF3, ws_H, S);

    // 2) All powers P^1..P^511 via doubling: 9 rounds.
    for (int r = 1; r <= 9; r++) {
        const int half = 1 << (r - 1);
        const int count = min(half, 511 - half);
        if (count <= 0) break;
        power_round_kernel<<<dim3(8, count), 256, 0, stream>>>(ws_Pw, half, count);
    }

    // 3) H_t = H_0 * P^t for all t in parallel (+ log -> output 3).
    hidden_kernel<<<T - 1, 256, 0, stream>>>(ws_H, ws_Pw, ws_H, out + OFF3);

    // 4) Fused observation GEMM + logs + chain-weighted reduction.
    obs_kernel<<<dim3(N / 128, T), 256, 0, stream>>>(ws_H, ws_pE, ws_pcw,
                                                     out + OFF1, out + OFF2);
}

// Round 2
// 568.885 us; speedup vs baseline: 2.6296x; 2.6296x over previous
//
#include <hip/hip_runtime.h>
#include <hip/hip_bf16.h>
#include <cmath>

// Problem constants (fixed by setup_inputs)
constexpr int S = 128;   // num_states
constexpr int C = 32;    // num_chains
constexpr int N = 4096;  // num_nodes
constexpr int T = 512;   // num_iters

// Output layout (flat float32, concatenated in reference return order)
constexpr size_t OFF1 = 0;                          // log_observed_state_probs  [T,N]
constexpr size_t OFF2 = OFF1 + (size_t)T * N;       // log_observed_state_probs_ [T,C,N]
constexpr size_t OFF3 = OFF2 + (size_t)T * C * N;   // log_hidden_state_probs   [T,C,S]
constexpr size_t OFF4 = OFF3 + (size_t)T * C * S;   // log_emission             [S,N]
constexpr size_t OFF5 = OFF4 + (size_t)S * N;       // log_chain_weights        [T,C]

typedef __bf16 bf16x8 __attribute__((ext_vector_type(8)));
typedef float floatx4 __attribute__((ext_vector_type(4)));

// ---------------------------------------------------------------------------
// Generic row log-softmax (block per row, 256 threads). Optional outputs:
//   log_out  : log_softmax, same layout
//   p_out    : softmax fp32, same layout
//   pb_out   : softmax bf16, same layout
//   pt_out   : softmax bf16 TRANSPOSED: pt_out[col*ldT + row]
// ---------------------------------------------------------------------------
__global__ void row_softmax_kernel(const float* __restrict__ in, int cols,
                                   float* __restrict__ log_out,
                                   float* __restrict__ p_out,
                                   __bf16* __restrict__ pb_out,
                                   __bf16* __restrict__ pt_out, int ldT) {
    const int row = blockIdx.x;
    const float* x = in + (size_t)row * cols;
    const int tid = threadIdx.x;

    __shared__ float sm[4];
    __shared__ float ss[4];

    float m = -INFINITY;
    for (int j = tid; j < cols; j += 256) m = fmaxf(m, x[j]);
#pragma unroll
    for (int o = 32; o > 0; o >>= 1) m = fmaxf(m, __shfl_xor(m, o, 64));
    const int wid = tid >> 6;
    if ((tid & 63) == 0) sm[wid] = m;
    __syncthreads();
    m = fmaxf(fmaxf(sm[0], sm[1]), fmaxf(sm[2], sm[3]));

    float s = 0.f;
    for (int j = tid; j < cols; j += 256) s += __expf(x[j] - m);
#pragma unroll
    for (int o = 32; o > 0; o >>= 1) s += __shfl_xor(s, o, 64);
    if ((tid & 63) == 0) ss[wid] = s;
    __syncthreads();
    s = ss[0] + ss[1] + ss[2] + ss[3];

    const float lse = m + __logf(s);
    for (int j = tid; j < cols; j += 256) {
        const float v = x[j] - lse;
        const float p = __expf(v);
        if (log_out) log_out[(size_t)row * cols + j] = v;
        if (p_out)   p_out[(size_t)row * cols + j] = p;
        if (pb_out)  pb_out[(size_t)row * cols + j] = (__bf16)p;
        if (pt_out)  pt_out[(size_t)j * ldT + row] = (__bf16)p;
    }
}

// ---------------------------------------------------------------------------
// Chain-weight softmax: one 64-thread block per row of 32.
// ---------------------------------------------------------------------------
__global__ void cw_softmax_kernel(const float* __restrict__ in,
                                  float* __restrict__ log_out,
                                  float* __restrict__ p_out) {
    const int row = blockIdx.x;
    const int j = threadIdx.x;
    const float* x = in + (size_t)row * C;

    float v = (j < C) ? x[j] : -INFINITY;
    float m = v;
#pragma unroll
    for (int o = 32; o > 0; o >>= 1) m = fmaxf(m, __shfl_xor(m, o, 64));
    float e = (j < C) ? __expf(v - m) : 0.f;
    float s = e;
#pragma unroll
    for (int o = 32; o > 0; o >>= 1) s += __shfl_xor(s, o, 64);
    const float lse = m + __logf(s);
    if (j < C) {
        const float lv = v - lse;
        log_out[(size_t)row * C + j] = lv;
        p_out[(size_t)row * C + j] = __expf(lv);
    }
}

// ---------------------------------------------------------------------------
// One H-doubling round (round r, m = 2^(r-1)):
//   blocks [0, count):        H_{m+j} = H_j * P^m   (+ bf16 copy + log->out3)
//   blocks [count, count+8):  P^{2m}  = P^m * P^m   (16 rows each)
// ---------------------------------------------------------------------------
__global__ void h_round_kernel(const float* __restrict__ Pcur,
                               float* __restrict__ Pnext,
                               float* __restrict__ Hall,
                               __bf16* __restrict__ Hb,
                               float* __restrict__ out3,
                               int m, int count) {
    const int b = blockIdx.x;
    const int col = threadIdx.x & 127;
    const int rg  = threadIdx.x >> 7;

    if (b < count) {
        const float* A = Hall + (size_t)b * (C * S);
        float acc[16];
#pragma unroll
        for (int r = 0; r < 16; r++) acc[r] = 0.f;
        for (int k = 0; k < S; k += 4) {
            const float b0 = Pcur[(size_t)(k + 0) * S + col];
            const float b1 = Pcur[(size_t)(k + 1) * S + col];
            const float b2 = Pcur[(size_t)(k + 2) * S + col];
            const float b3 = Pcur[(size_t)(k + 3) * S + col];
#pragma unroll
            for (int r = 0; r < 16; r++) {
                const float4 a = *reinterpret_cast<const float4*>(&A[(size_t)(rg * 16 + r) * S + k]);
                acc[r] = fmaf(a.x, b0, fmaf(a.y, b1, fmaf(a.z, b2, fmaf(a.w, b3, acc[r]))));
            }
        }
        const size_t t = (size_t)m + b;
#pragma unroll
        for (int r = 0; r < 16; r++) {
            const int c = rg * 16 + r;
            const float p = acc[r];
            Hall[(t * C + c) * S + col] = p;
            Hb[(t * C + c) * S + col] = (__bf16)p;
            out3[(t * C + c) * S + col] = __logf(p);
        }
    } else {
        const int rb = b - count;
        const int row0 = rb * 16 + rg * 8;
        float acc[8];
#pragma unroll
        for (int r = 0; r < 8; r++) acc[r] = 0.f;
        for (int k = 0; k < S; k += 4) {
            const float b0 = Pcur[(size_t)(k + 0) * S + col];
            const float b1 = Pcur[(size_t)(k + 1) * S + col];
            const float b2 = Pcur[(size_t)(k + 2) * S + col];
            const float b3 = Pcur[(size_t)(k + 3) * S + col];
#pragma unroll
            for (int r = 0; r < 8; r++) {
                const float4 a = *reinterpret_cast<const float4*>(&Pcur[(size_t)(row0 + r) * S + k]);
                acc[r] = fmaf(a.x, b0, fmaf(a.y, b1, fmaf(a.z, b2, fmaf(a.w, b3, acc[r]))));
            }
        }
#pragma unroll
        for (int r = 0; r < 8; r++) Pnext[(size_t)(row0 + r) * S + col] = acc[r];
    }
}

// ---------------------------------------------------------------------------
// Observation GEMM via MFMA bf16 + fused epilogue.
// Per block: one t, 256 n-columns. 4 waves, each wave a 32x64 output tile.
// A-frag: Hb[t] rows (contiguous 8 bf16 per lane); B-frag: pET rows.
//   out2[t,c,n] = log(O[c,n]);  out1[t,n] = log(sum_c pcw[t,c]*O[c,n])
// ---------------------------------------------------------------------------
__global__ __launch_bounds__(256) void obs_mfma_kernel(
        const __bf16* __restrict__ Hb,    // [T,C,S]
        const __bf16* __restrict__ pET,   // [N,S]
        const float* __restrict__ pcw,    // [T,C]
        float* __restrict__ out1,
        float* __restrict__ out2) {
    const int t = blockIdx.y;
    const int w = threadIdx.x >> 6;
    const int lane = threadIdx.x & 63;
    const int lr = lane & 15;
    const int quad = lane >> 4;
    const int nbase = blockIdx.x * 256 + w * 64;

    __shared__ float sw[C];
    if (threadIdx.x < C) sw[threadIdx.x] = pcw[(size_t)t * C + threadIdx.x];
    __syncthreads();

    const __bf16* A = Hb + (size_t)t * C * S;

    floatx4 acc[2][4];
#pragma unroll
    for (int mt = 0; mt < 2; mt++)
#pragma unroll
        for (int nt = 0; nt < 4; nt++) acc[mt][nt] = (floatx4)0.f;

#pragma unroll
    for (int kt = 0; kt < 4; kt++) {
        const int ko = kt * 32 + quad * 8;
        const bf16x8 a0 = *reinterpret_cast<const bf16x8*>(&A[(size_t)(lr) * S + ko]);
        const bf16x8 a1 = *reinterpret_cast<const bf16x8*>(&A[(size_t)(16 + lr) * S + ko]);
        const bf16x8 b0 = *reinterpret_cast<const bf16x8*>(&pET[(size_t)(nbase +  0 + lr) * S + ko]);
        const bf16x8 b1 = *reinterpret_cast<const bf16x8*>(&pET[(size_t)(nbase + 16 + lr) * S + ko]);
        const bf16x8 b2 = *reinterpret_cast<const bf16x8*>(&pET[(size_t)(nbase + 32 + lr) * S + ko]);
        const bf16x8 b3 = *reinterpret_cast<const bf16x8*>(&pET[(size_t)(nbase + 48 + lr) * S + ko]);
        acc[0][0] = __builtin_amdgcn_mfma_f32_16x16x32_bf16(a0, b0, acc[0][0], 0, 0, 0);
        acc[0][1] = __builtin_amdgcn_mfma_f32_16x16x32_bf16(a0, b1, acc[0][1], 0, 0, 0);
        acc[0][2] = __builtin_amdgcn_mfma_f32_16x16x32_bf16(a0, b2, acc[0][2], 0, 0, 0);
        acc[0][3] = __builtin_amdgcn_mfma_f32_16x16x32_bf16(a0, b3, acc[0][3], 0, 0, 0);
        acc[1][0] = __builtin_amdgcn_mfma_f32_16x16x32_bf16(a1, b0, acc[1][0], 0, 0, 0);
        acc[1][1] = __builtin_amdgcn_mfma_f32_16x16x32_bf16(a1, b1, acc[1][1], 0, 0, 0);
        acc[1][2] = __builtin_amdgcn_mfma_f32_16x16x32_bf16(a1, b2, acc[1][2], 0, 0, 0);
        acc[1][3] = __builtin_amdgcn_mfma_f32_16x16x32_bf16(a1, b3, acc[1][3], 0, 0, 0);
    }

    // Epilogue: logs to out2, weighted chain-sum to out1.
    float part[4] = {0.f, 0.f, 0.f, 0.f};
#pragma unroll
    for (int mt = 0; mt < 2; mt++) {
#pragma unroll
        for (int nt = 0; nt < 4; nt++) {
#pragma unroll
            for (int reg = 0; reg < 4; reg++) {
                const int c = mt * 16 + quad * 4 + reg;
                const int n = nbase + nt * 16 + lr;
                const float o = acc[mt][nt][reg];
                out2[((size_t)t * C + c) * N + n] = __logf(o);
                part[nt] = fmaf(sw[c], o, part[nt]);
            }
        }
    }
#pragma unroll
    for (int nt = 0; nt < 4; nt++) {
        float v = part[nt];
        v += __shfl_xor(v, 16, 64);
        v += __shfl_xor(v, 32, 64);
        if (quad == 0) {
            out1[(size_t)t * N + nbase + nt * 16 + lr] = __logf(v);
        }
    }
}

// ---------------------------------------------------------------------------
extern "C" void kernel_launch(void* const* d_in, const int* in_sizes, int n_in,
                              void* d_out, int out_size, void* d_ws, size_t ws_size,
                              hipStream_t stream) {
    const float* in_init  = (const float*)d_in[0];  // [C,S]
    const float* in_cw    = (const float*)d_in[1];  // [T,C]
    const float* in_emis  = (const float*)d_in[2];  // [S,N]
    const float* in_trans = (const float*)d_in[3];  // [S,S]

    float* out = (float*)d_out;

    // Workspace layout (~13.2 MB; all 16B-aligned)
    char* wsb = (char*)d_ws;
    float*  Pbuf   = (float*)wsb;                                   // 2 x [S,S] fp32, 128 KB
    float*  ws_pcw = (float*)(wsb + 128 * 1024);                    // [T,C] fp32, 64 KB
    float*  ws_H   = (float*)(wsb + 192 * 1024);                    // [T,C,S] fp32, 8 MB
    __bf16* ws_Hb  = (__bf16*)(wsb + 192 * 1024 + 8u * 1024 * 1024);  // [T,C,S] bf16, 4 MB
    __bf16* ws_pET = (__bf16*)(wsb + 192 * 1024 + 12u * 1024 * 1024); // [N,S] bf16, 1 MB

    // 1) Softmaxes. Log parts go straight to outputs, prob parts to ws.
    row_softmax_kernel<<<S, 256, 0, stream>>>(in_emis, N, out + OFF4, nullptr, nullptr, ws_pET, S);
    cw_softmax_kernel<<<T, 64, 0, stream>>>(in_cw, out + OFF5, ws_pcw);
    row_softmax_kernel<<<S, 256, 0, stream>>>(in_trans, S, nullptr, Pbuf, nullptr, nullptr, 0);
    row_softmax_kernel<<<C, 256, 0, stream>>>(in_init, S, out + OFF3, ws_H, ws_Hb, nullptr, 0);

    // 2) H-doubling: round r has m=2^(r-1); H_{m+j} = H_j * P^m for j<count,
    //    plus 8 blocks computing P^{2m} (skipped on the last round).
    for (int r = 1; r <= 9; r++) {
        const int m = 1 << (r - 1);
        const int count = (m < T - m) ? m : (T - m);
        const float* Pc = Pbuf + (size_t)((r - 1) & 1) * (S * S);
        float* Pn = Pbuf + (size_t)(r & 1) * (S * S);
        const int extra = (r < 9) ? 8 : 0;
        h_round_kernel<<<count + extra, 256, 0, stream>>>(Pc, Pn, ws_H, ws_Hb,
                                                          out + OFF3, m, count);
    }

    // 3) Observation GEMM (bf16 MFMA) + fused logs + chain reduction.
    obs_mfma_kernel<<<dim3(N / 256, T), 256, 0, stream>>>(ws_Hb, ws_pET, ws_pcw,
                                                          out + OFF1, out + OFF2);
}

// Round 3
// 415.458 us; speedup vs baseline: 3.6007x; 1.3693x over previous
//
#include <hip/hip_runtime.h>
#include <hip/hip_bf16.h>
#include <cmath>

// Problem constants (fixed by setup_inputs)
constexpr int S = 128;   // num_states
constexpr int C = 32;    // num_chains
constexpr int N = 4096;  // num_nodes
constexpr int T = 512;   // num_iters

// Output layout (flat float32, concatenated in reference return order)
constexpr size_t OFF1 = 0;                          // log_observed_state_probs  [T,N]
constexpr size_t OFF2 = OFF1 + (size_t)T * N;       // log_observed_state_probs_ [T,C,N]
constexpr size_t OFF3 = OFF2 + (size_t)T * C * N;   // log_hidden_state_probs   [T,C,S]
constexpr size_t OFF4 = OFF3 + (size_t)T * C * S;   // log_emission             [S,N]
constexpr size_t OFF5 = OFF4 + (size_t)S * N;       // log_chain_weights        [T,C]

typedef __bf16 bf16x8 __attribute__((ext_vector_type(8)));
typedef float floatx4 __attribute__((ext_vector_type(4)));

__device__ __forceinline__ void split_bf16(float p, __bf16& hi, __bf16& lo) {
    hi = (__bf16)p;
    lo = (__bf16)(p - (float)hi);
}

// ---------------------------------------------------------------------------
// Fused softmax kernel, one launch, 352 blocks x 256 threads:
//   [0,128)   emission rows (4096 cols): log->out4, bf16 transposed -> pET[N,S]
//   [128,256) transition rows (128 cols): hi/lo pair row-major (R) + transposed (Tt)
//   [256,288) init rows (128 cols): log->out3[t=0], hi/lo pair -> Hhi/Hlo[t=0]
//   [288,352) chain weights, 8 rows/block of 32 cols: log->out5, fp32 -> pcw
// ---------------------------------------------------------------------------
__global__ __launch_bounds__(256) void fused_softmax_kernel(
        const float* __restrict__ emis, const float* __restrict__ cw,
        const float* __restrict__ trans, const float* __restrict__ init,
        float* __restrict__ out3, float* __restrict__ out4, float* __restrict__ out5,
        __bf16* __restrict__ pET, float* __restrict__ pcw,
        __bf16* __restrict__ Rhi, __bf16* __restrict__ Rlo,
        __bf16* __restrict__ Thi, __bf16* __restrict__ Tlo,
        __bf16* __restrict__ Hhi, __bf16* __restrict__ Hlo) {
    const int b = blockIdx.x;
    const int tid = threadIdx.x;

    if (b >= 288) {   // ---- chain weights: 8 rows of 32 per block ----
        const int row = (b - 288) * 8 + (tid >> 5);
        const int j = tid & 31;
        const float v = cw[(size_t)row * C + j];
        float m = v;
#pragma unroll
        for (int o = 16; o > 0; o >>= 1) m = fmaxf(m, __shfl_xor(m, o, 64));
        float s = __expf(v - m);
#pragma unroll
        for (int o = 16; o > 0; o >>= 1) s += __shfl_xor(s, o, 64);
        const float lv = v - m - __logf(s);
        out5[(size_t)row * C + j] = lv;
        pcw[(size_t)row * C + j] = __expf(lv);
        return;
    }

    // ---- generic block softmax over `cols` ----
    const float* x;
    int cols, row;
    if (b < 128)      { row = b;       cols = N; x = emis  + (size_t)row * N; }
    else if (b < 256) { row = b - 128; cols = S; x = trans + (size_t)row * S; }
    else              { row = b - 256; cols = S; x = init  + (size_t)row * S; }

    __shared__ float sm[4];
    __shared__ float ss[4];

    float m = -INFINITY;
    for (int j = tid; j < cols; j += 256) m = fmaxf(m, x[j]);
#pragma unroll
    for (int o = 32; o > 0; o >>= 1) m = fmaxf(m, __shfl_xor(m, o, 64));
    const int wid = tid >> 6;
    if ((tid & 63) == 0) sm[wid] = m;
    __syncthreads();
    m = fmaxf(fmaxf(sm[0], sm[1]), fmaxf(sm[2], sm[3]));

    float s = 0.f;
    for (int j = tid; j < cols; j += 256) s += __expf(x[j] - m);
#pragma unroll
    for (int o = 32; o > 0; o >>= 1) s += __shfl_xor(s, o, 64);
    if ((tid & 63) == 0) ss[wid] = s;
    __syncthreads();
    s = ss[0] + ss[1] + ss[2] + ss[3];
    const float lse = m + __logf(s);

    for (int j = tid; j < cols; j += 256) {
        const float v = x[j] - lse;
        const float p = __expf(v);
        if (b < 128) {          // emission
            out4[(size_t)row * N + j] = v;
            pET[(size_t)j * S + row] = (__bf16)p;
        } else if (b < 256) {   // transition -> P^1 pair, both layouts
            __bf16 hi, lo; split_bf16(p, hi, lo);
            Rhi[(size_t)row * S + j] = hi; Rlo[(size_t)row * S + j] = lo;
            Thi[(size_t)j * S + row] = hi; Tlo[(size_t)j * S + row] = lo;
        } else {                // init -> H_0
            out3[((size_t)0 * C + row) * S + j] = v;
            __bf16 hi, lo; split_bf16(p, hi, lo);
            Hhi[(size_t)row * S + j] = hi; Hlo[(size_t)row * S + j] = lo;
        }
    }
}

// ---------------------------------------------------------------------------
// One H-doubling round (m = 2^(r-1)), MFMA with bf16 hi/lo pairs (3 MFMAs per
// product -> ~fp32 accuracy):
//   blocks [0, count):       H_{m+b} = H_b * P^m   (+ pair store + log->out3)
//   blocks [count, count+8): P^{2m}  = P^m * P^m   (16 rows each, both layouts)
// A-operand: row-major pair (H or R). B-operand: transposed pair (T).
// ---------------------------------------------------------------------------
__global__ __launch_bounds__(256) void h_round_kernel(
        const __bf16* __restrict__ Rhi, const __bf16* __restrict__ Rlo,
        const __bf16* __restrict__ Thi, const __bf16* __restrict__ Tlo,
        __bf16* __restrict__ Rnhi, __bf16* __restrict__ Rnlo,
        __bf16* __restrict__ Tnhi, __bf16* __restrict__ Tnlo,
        __bf16* __restrict__ Hhi, __bf16* __restrict__ Hlo,
        float* __restrict__ out3, int m, int count) {
    const int b = blockIdx.x;
    const int w = threadIdx.x >> 6;
    const int lane = threadIdx.x & 63;
    const int lr = lane & 15;
    const int quad = lane >> 4;

    if (b < count) {
        const __bf16* Ahi = Hhi + (size_t)b * C * S;
        const __bf16* Alo = Hlo + (size_t)b * C * S;
        floatx4 acc[2][2];
#pragma unroll
        for (int mt = 0; mt < 2; mt++)
#pragma unroll
            for (int nt = 0; nt < 2; nt++) acc[mt][nt] = (floatx4)0.f;

#pragma unroll
        for (int kt = 0; kt < 4; kt++) {
            const int ko = kt * 32 + quad * 8;
            const bf16x8 ah0 = *reinterpret_cast<const bf16x8*>(&Ahi[(size_t)lr * S + ko]);
            const bf16x8 ah1 = *reinterpret_cast<const bf16x8*>(&Ahi[(size_t)(16 + lr) * S + ko]);
            const bf16x8 al0 = *reinterpret_cast<const bf16x8*>(&Alo[(size_t)lr * S + ko]);
            const bf16x8 al1 = *reinterpret_cast<const bf16x8*>(&Alo[(size_t)(16 + lr) * S + ko]);
            const bf16x8 bh0 = *reinterpret_cast<const bf16x8*>(&Thi[(size_t)(w * 32 + lr) * S + ko]);
            const bf16x8 bh1 = *reinterpret_cast<const bf16x8*>(&Thi[(size_t)(w * 32 + 16 + lr) * S + ko]);
            const bf16x8 bl0 = *reinterpret_cast<const bf16x8*>(&Tlo[(size_t)(w * 32 + lr) * S + ko]);
            const bf16x8 bl1 = *reinterpret_cast<const bf16x8*>(&Tlo[(size_t)(w * 32 + 16 + lr) * S + ko]);
            acc[0][0] = __builtin_amdgcn_mfma_f32_16x16x32_bf16(ah0, bh0, acc[0][0], 0, 0, 0);
            acc[0][0] = __builtin_amdgcn_mfma_f32_16x16x32_bf16(ah0, bl0, acc[0][0], 0, 0, 0);
            acc[0][0] = __builtin_amdgcn_mfma_f32_16x16x32_bf16(al0, bh0, acc[0][0], 0, 0, 0);
            acc[0][1] = __builtin_amdgcn_mfma_f32_16x16x32_bf16(ah0, bh1, acc[0][1], 0, 0, 0);
            acc[0][1] = __builtin_amdgcn_mfma_f32_16x16x32_bf16(ah0, bl1, acc[0][1], 0, 0, 0);
            acc[0][1] = __builtin_amdgcn_mfma_f32_16x16x32_bf16(al0, bh1, acc[0][1], 0, 0, 0);
            acc[1][0] = __builtin_amdgcn_mfma_f32_16x16x32_bf16(ah1, bh0, acc[1][0], 0, 0, 0);
            acc[1][0] = __builtin_amdgcn_mfma_f32_16x16x32_bf16(ah1, bl0, acc[1][0], 0, 0, 0);
            acc[1][0] = __builtin_amdgcn_mfma_f32_16x16x32_bf16(al1, bh0, acc[1][0], 0, 0, 0);
            acc[1][1] = __builtin_amdgcn_mfma_f32_16x16x32_bf16(ah1, bh1, acc[1][1], 0, 0, 0);
            acc[1][1] = __builtin_amdgcn_mfma_f32_16x16x32_bf16(ah1, bl1, acc[1][1], 0, 0, 0);
            acc[1][1] = __builtin_amdgcn_mfma_f32_16x16x32_bf16(al1, bh1, acc[1][1], 0, 0, 0);
        }

        const size_t t = (size_t)m + b;
#pragma unroll
        for (int mt = 0; mt < 2; mt++) {
#pragma unroll
            for (int nt = 0; nt < 2; nt++) {
#pragma unroll
                for (int reg = 0; reg < 4; reg++) {
                    const int c = mt * 16 + quad * 4 + reg;
                    const int n = w * 32 + nt * 16 + lr;
                    const float p = acc[mt][nt][reg];
                    __bf16 hi, lo; split_bf16(p, hi, lo);
                    Hhi[(t * C + c) * S + n] = hi;
                    Hlo[(t * C + c) * S + n] = lo;
                    out3[(t * C + c) * S + n] = __logf(p);
                }
            }
        }
    } else {
        // ---- squaring: P^{2m} = P^m * P^m, 16 output rows per block ----
        const int rb = b - count;
        floatx4 acc[2];
        acc[0] = (floatx4)0.f; acc[1] = (floatx4)0.f;
#pragma unroll
        for (int kt = 0; kt < 4; kt++) {
            const int ko = kt * 32 + quad * 8;
            const bf16x8 ah = *reinterpret_cast<const bf16x8*>(&Rhi[(size_t)(rb * 16 + lr) * S + ko]);
            const bf16x8 al = *reinterpret_cast<const bf16x8*>(&Rlo[(size_t)(rb * 16 + lr) * S + ko]);
            const bf16x8 bh0 = *reinterpret_cast<const bf16x8*>(&Thi[(size_t)(w * 32 + lr) * S + ko]);
            const bf16x8 bh1 = *reinterpret_cast<const bf16x8*>(&Thi[(size_t)(w * 32 + 16 + lr) * S + ko]);
            const bf16x8 bl0 = *reinterpret_cast<const bf16x8*>(&Tlo[(size_t)(w * 32 + lr) * S + ko]);
            const bf16x8 bl1 = *reinterpret_cast<const bf16x8*>(&Tlo[(size_t)(w * 32 + 16 + lr) * S + ko]);
            acc[0] = __builtin_amdgcn_mfma_f32_16x16x32_bf16(ah, bh0, acc[0], 0, 0, 0);
            acc[0] = __builtin_amdgcn_mfma_f32_16x16x32_bf16(ah, bl0, acc[0], 0, 0, 0);
            acc[0] = __builtin_amdgcn_mfma_f32_16x16x32_bf16(al, bh0, acc[0], 0, 0, 0);
            acc[1] = __builtin_amdgcn_mfma_f32_16x16x32_bf16(ah, bh1, acc[1], 0, 0, 0);
            acc[1] = __builtin_amdgcn_mfma_f32_16x16x32_bf16(ah, bl1, acc[1], 0, 0, 0);
            acc[1] = __builtin_amdgcn_mfma_f32_16x16x32_bf16(al, bh1, acc[1], 0, 0, 0);
        }
#pragma unroll
        for (int nt = 0; nt < 2; nt++) {
#pragma unroll
            for (int reg = 0; reg < 4; reg++) {
                const int row = rb * 16 + quad * 4 + reg;
                const int col = w * 32 + nt * 16 + lr;
                const float p = acc[nt][reg];
                __bf16 hi, lo; split_bf16(p, hi, lo);
                Rnhi[(size_t)row * S + col] = hi; Rnlo[(size_t)row * S + col] = lo;
                Tnhi[(size_t)col * S + row] = hi; Tnlo[(size_t)col * S + row] = lo;
            }
        }
    }
}

// ---------------------------------------------------------------------------
// Observation GEMM via MFMA bf16 + fused epilogue (unchanged from R2; reads
// the hi plane of the H pair).
// ---------------------------------------------------------------------------
__global__ __launch_bounds__(256) void obs_mfma_kernel(
        const __bf16* __restrict__ Hb,    // [T,C,S] (hi plane)
        const __bf16* __restrict__ pET,   // [N,S]
        const float* __restrict__ pcw,    // [T,C]
        float* __restrict__ out1,
        float* __restrict__ out2) {
    const int t = blockIdx.y;
    const int w = threadIdx.x >> 6;
    const int lane = threadIdx.x & 63;
    const int lr = lane & 15;
    const int quad = lane >> 4;
    const int nbase = blockIdx.x * 256 + w * 64;

    __shared__ float sw[C];
    if (threadIdx.x < C) sw[threadIdx.x] = pcw[(size_t)t * C + threadIdx.x];
    __syncthreads();

    const __bf16* A = Hb + (size_t)t * C * S;

    floatx4 acc[2][4];
#pragma unroll
    for (int mt = 0; mt < 2; mt++)
#pragma unroll
        for (int nt = 0; nt < 4; nt++) acc[mt][nt] = (floatx4)0.f;

#pragma unroll
    for (int kt = 0; kt < 4; kt++) {
        const int ko = kt * 32 + quad * 8;
        const bf16x8 a0 = *reinterpret_cast<const bf16x8*>(&A[(size_t)(lr) * S + ko]);
        const bf16x8 a1 = *reinterpret_cast<const bf16x8*>(&A[(size_t)(16 + lr) * S + ko]);
        const bf16x8 b0 = *reinterpret_cast<const bf16x8*>(&pET[(size_t)(nbase +  0 + lr) * S + ko]);
        const bf16x8 b1 = *reinterpret_cast<const bf16x8*>(&pET[(size_t)(nbase + 16 + lr) * S + ko]);
        const bf16x8 b2 = *reinterpret_cast<const bf16x8*>(&pET[(size_t)(nbase + 32 + lr) * S + ko]);
        const bf16x8 b3 = *reinterpret_cast<const bf16x8*>(&pET[(size_t)(nbase + 48 + lr) * S + ko]);
        acc[0][0] = __builtin_amdgcn_mfma_f32_16x16x32_bf16(a0, b0, acc[0][0], 0, 0, 0);
        acc[0][1] = __builtin_amdgcn_mfma_f32_16x16x32_bf16(a0, b1, acc[0][1], 0, 0, 0);
        acc[0][2] = __builtin_amdgcn_mfma_f32_16x16x32_bf16(a0, b2, acc[0][2], 0, 0, 0);
        acc[0][3] = __builtin_amdgcn_mfma_f32_16x16x32_bf16(a0, b3, acc[0][3], 0, 0, 0);
        acc[1][0] = __builtin_amdgcn_mfma_f32_16x16x32_bf16(a1, b0, acc[1][0], 0, 0, 0);
        acc[1][1] = __builtin_amdgcn_mfma_f32_16x16x32_bf16(a1, b1, acc[1][1], 0, 0, 0);
        acc[1][2] = __builtin_amdgcn_mfma_f32_16x16x32_bf16(a1, b2, acc[1][2], 0, 0, 0);
        acc[1][3] = __builtin_amdgcn_mfma_f32_16x16x32_bf16(a1, b3, acc[1][3], 0, 0, 0);
    }

    float part[4] = {0.f, 0.f, 0.f, 0.f};
#pragma unroll
    for (int mt = 0; mt < 2; mt++) {
#pragma unroll
        for (int nt = 0; nt < 4; nt++) {
#pragma unroll
            for (int reg = 0; reg < 4; reg++) {
                const int c = mt * 16 + quad * 4 + reg;
                const int n = nbase + nt * 16 + lr;
                const float o = acc[mt][nt][reg];
                out2[((size_t)t * C + c) * N + n] = __logf(o);
                part[nt] = fmaf(sw[c], o, part[nt]);
            }
        }
    }
#pragma unroll
    for (int nt = 0; nt < 4; nt++) {
        float v = part[nt];
        v += __shfl_xor(v, 16, 64);
        v += __shfl_xor(v, 32, 64);
        if (quad == 0) {
            out1[(size_t)t * N + nbase + nt * 16 + lr] = __logf(v);
        }
    }
}

// ---------------------------------------------------------------------------
extern "C" void kernel_launch(void* const* d_in, const int* in_sizes, int n_in,
                              void* d_out, int out_size, void* d_ws, size_t ws_size,
                              hipStream_t stream) {
    const float* in_init  = (const float*)d_in[0];  // [C,S]
    const float* in_cw    = (const float*)d_in[1];  // [T,C]
    const float* in_emis  = (const float*)d_in[2];  // [S,N]
    const float* in_trans = (const float*)d_in[3];  // [S,S]

    float* out = (float*)d_out;

    // Workspace layout (~9.3 MB, 256B aligned)
    char* wsb = (char*)d_ws;
    float*  ws_pcw = (float*)(wsb);                                  // 64 KB [T,C]
    __bf16* ws_pET = (__bf16*)(wsb + (64u << 10));                   // 1 MB  [N,S]
    __bf16* ws_Hhi = (__bf16*)(wsb + (1088u << 10));                 // 4 MB  [T,C,S]
    __bf16* ws_Hlo = (__bf16*)(wsb + (5184u << 10));                 // 4 MB  [T,C,S]
    // Two power slots, each {Rhi,Rlo,Thi,Tlo} of 32 KB
    __bf16* Pslot[2][4];
    for (int sl = 0; sl < 2; sl++)
        for (int pl = 0; pl < 4; pl++)
            Pslot[sl][pl] = (__bf16*)(wsb + (9280u << 10) + (size_t)(sl * 4 + pl) * (32u << 10));

    // 1) All softmaxes in one launch.
    fused_softmax_kernel<<<352, 256, 0, stream>>>(
        in_emis, in_cw, in_trans, in_init,
        out + OFF3, out + OFF4, out + OFF5,
        ws_pET, ws_pcw,
        Pslot[0][0], Pslot[0][1], Pslot[0][2], Pslot[0][3],
        ws_Hhi, ws_Hlo);

    // 2) H-doubling rounds (hi/lo-pair MFMA), squaring fused as +8 blocks.
    for (int r = 1; r <= 9; r++) {
        const int m = 1 << (r - 1);
        const int count = (m < T - m) ? m : (T - m);
        const int s = (r - 1) & 1, d = r & 1;
        const int extra = (r < 9) ? 8 : 0;
        h_round_kernel<<<count + extra, 256, 0, stream>>>(
            Pslot[s][0], Pslot[s][1], Pslot[s][2], Pslot[s][3],
            Pslot[d][0], Pslot[d][1], Pslot[d][2], Pslot[d][3],
            ws_Hhi, ws_Hlo, out + OFF3, m, count);
    }

    // 3) Observation GEMM (bf16 MFMA) + fused logs + chain reduction.
    obs_mfma_kernel<<<dim3(N / 256, T), 256, 0, stream>>>(ws_Hhi, ws_pET, ws_pcw,
                                                          out + OFF1, out + OFF2);
}